// Round 9
// baseline (5402.846 us; speedup 1.0000x reference)
//
#include <hip/hip_runtime.h>

// ComplexLSTM: B=32,S=512,I=512,H=512
// ws layout (bytes)
#define OFF_WZT   0ull
#define OFF_WHT   5242880ull
#define OFF_BIAS  10485760ull
#define OFF_XPERM 10496000ull
#define OFF_HBUF  94382080ull   // 8 domains x 2 bufs x 2048 u64 = 262144 B
#define OFF_SENT  94644224ull   // 8 domains x 64 u32 = 2048 B
#define NWG 512

typedef __attribute__((ext_vector_type(8))) short short8;
typedef __attribute__((ext_vector_type(4))) float f32x4;

__device__ __forceinline__ unsigned short f2bf(float f) {
  unsigned int u = __float_as_uint(f);
  u += 0x7fffu + ((u >> 16) & 1u);
  return (unsigned short)(u >> 16);
}
__device__ __forceinline__ float bf2f(unsigned short h) {
  return __uint_as_float(((unsigned int)h) << 16);
}

struct PackArgs {
  const float* zlo[5]; const float* zhi[5];
  const float* hlo[5]; const float* hhi[5];
  const float* bias[5];
};

// WzT[c][k]: k<512 -> z_r coeff (col k), k>=512 -> z_i coeff.
// WhT[c][k]: K interleaved: k=2*kk+ri, ri=0 -> h_r[kk] coeff, ri=1 -> h_i[kk] coeff.
// c = g*512+h (g: 0=i,1=f,2=o,3=cr,4=ci)
__global__ void pack_kernel(PackArgs args, unsigned short* __restrict__ WzT,
                            unsigned short* __restrict__ WhT,
                            float* __restrict__ bias_out,
                            unsigned long long* __restrict__ Hbuf64,
                            unsigned int* __restrict__ Sent) {
  const long long total = 2ll * 2621440ll;
  long long stride = (long long)gridDim.x * blockDim.x;
  for (long long gid = (long long)blockIdx.x * blockDim.x + threadIdx.x; gid < total; gid += stride) {
    int sel = (int)(gid >= 2621440ll);
    int e = (int)(gid - (long long)sel * 2621440ll);
    int c = e >> 10, k = e & 1023;
    int g = c >> 9, h = c & 511;
    float v;
    if (sel) { // WhT interleaved
      int kk = k >> 1, ri = k & 1;
      const float* src = ri ? args.hhi[g] : args.hlo[g];
      float sgn = (!ri || g == 4) ? 1.f : -1.f;
      v = sgn * src[kk * 512 + h];
    } else {   // WzT block layout
      int kk = k & 511;
      const float* src = (k < 512) ? args.zlo[g] : args.zhi[g];
      float sgn = (k < 512 || g == 4) ? 1.f : -1.f;
      v = sgn * src[kk * 512 + h];
    }
    (sel ? WhT : WzT)[(long long)c * 1024 + k] = f2bf(v);
  }
  int gid0 = blockIdx.x * blockDim.x + threadIdx.x;
  if (gid0 < 2560) { int g = gid0 >> 9; bias_out[gid0] = args.bias[g][gid0 & 511]; }
  if (gid0 < 32768) Hbuf64[gid0] = 0ull; // clear all data tags (replay safety)
  if (gid0 < 512) Sent[gid0] = 0u;       // clear sentinels
}

// Phase 1: X = [z_r|z_i](16384x1024) @ WzT^T + bias -> bf16, permuted to
// [t][wgc][b][40] with gate-major inner order g*8+jj.
__global__ __launch_bounds__(256) void phase1_kernel(
    const float* __restrict__ zr, const float* __restrict__ zi,
    const unsigned short* __restrict__ WzT, const float* __restrict__ bias,
    unsigned short* __restrict__ Xperm) {
  __shared__ unsigned short Al[64 * 40];
  __shared__ unsigned short Bl[64 * 40];
  int bid = blockIdx.x;
  int bm = bid / 40, bn = bid % 40;
  int tid = threadIdx.x;
  int wave = tid >> 6, lane = tid & 63;
  int mq = wave >> 1, nq = wave & 1;
  int lr = lane & 15, lkb = (lane >> 4) * 8;
  int srow = tid >> 2, sq = tid & 3;

  f32x4 acc[2][2];
#pragma unroll
  for (int i0 = 0; i0 < 2; i0++)
#pragma unroll
    for (int j0 = 0; j0 < 2; j0++) acc[i0][j0] = (f32x4){0.f, 0.f, 0.f, 0.f};

  for (int kb = 0; kb < 32; kb++) {
    int gk = kb * 32 + sq * 8;
    const float* srcp = (gk < 512) ? (zr + (long long)(bm * 64 + srow) * 512 + gk)
                                   : (zi + (long long)(bm * 64 + srow) * 512 + (gk - 512));
    float4 f0 = *(const float4*)srcp;
    float4 f1 = *(const float4*)(srcp + 4);
    uint4 p;
    p.x = (unsigned)f2bf(f0.x) | ((unsigned)f2bf(f0.y) << 16);
    p.y = (unsigned)f2bf(f0.z) | ((unsigned)f2bf(f0.w) << 16);
    p.z = (unsigned)f2bf(f1.x) | ((unsigned)f2bf(f1.y) << 16);
    p.w = (unsigned)f2bf(f1.z) | ((unsigned)f2bf(f1.w) << 16);
    *(uint4*)(&Al[srow * 40 + sq * 8]) = p;
    const unsigned short* bsrc = WzT + (long long)(bn * 64 + srow) * 1024 + kb * 32 + sq * 8;
    *(uint4*)(&Bl[srow * 40 + sq * 8]) = *(const uint4*)bsrc;
    __syncthreads();
    short8 a0 = *(const short8*)(&Al[(mq * 32 + 0 + lr) * 40 + lkb]);
    short8 a1 = *(const short8*)(&Al[(mq * 32 + 16 + lr) * 40 + lkb]);
    short8 b0 = *(const short8*)(&Bl[(nq * 32 + 0 + lr) * 40 + lkb]);
    short8 b1 = *(const short8*)(&Bl[(nq * 32 + 16 + lr) * 40 + lkb]);
    acc[0][0] = __builtin_amdgcn_mfma_f32_16x16x32_bf16(a0, b0, acc[0][0], 0, 0, 0);
    acc[0][1] = __builtin_amdgcn_mfma_f32_16x16x32_bf16(a0, b1, acc[0][1], 0, 0, 0);
    acc[1][0] = __builtin_amdgcn_mfma_f32_16x16x32_bf16(a1, b0, acc[1][0], 0, 0, 0);
    acc[1][1] = __builtin_amdgcn_mfma_f32_16x16x32_bf16(a1, b1, acc[1][1], 0, 0, 0);
    __syncthreads();
  }
#pragma unroll
  for (int mt = 0; mt < 2; mt++)
#pragma unroll
    for (int nt = 0; nt < 2; nt++) {
      int C = bn * 64 + nq * 32 + nt * 16 + lr;
      float bv = bias[C];
      int g = C >> 9, h = C & 511;
      int wgc = h >> 3, jj = h & 7;
#pragma unroll
      for (int r = 0; r < 4; r++) {
        int R = bm * 64 + mq * 32 + mt * 16 + (lane >> 4) * 4 + r;
        int bb = R >> 9, tt = R & 511;
        float v = acc[mt][nt][r] + bv;
        Xperm[(((long long)(tt * 64 + wgc)) * 32 + bb) * 40 + g * 8 + jj] = f2bf(v);
      }
    }
}

// Phase 2: 8 sync domains (4 batch rows each) x 64 WGs x 384 thr (2 WG/CU).
// WG (d,wl) owns hidden cols [8wl,8wl+8) for rows [4d,4d+4).
// Data: tagged u64 chunks (tag=t+1)<<32 | (bf16 hr|hi<<16), 2048/domain/buf;
// chunk i for (row r<4, col j): i = (j>>2)*16 + r*4 + (j&3) (fragment-major,
// identity with LDS Hl layout). Sentinel: Sent[d*64+wl] = t+1 stored AFTER
// vmcnt(0) drain of the 32 data stores -> consumers poll 64 sentinels only
// (1 load/lane/pass), then one bulk tagged read (verify-retry ~never).
__global__ __launch_bounds__(384, 3) void recur_kernel(
    const unsigned short* __restrict__ WhT,
    const unsigned short* __restrict__ Xperm,
    unsigned long long* __restrict__ Hbuf64,
    unsigned int* __restrict__ Sent,
    float* __restrict__ out) {
  __shared__ unsigned int Hl32[2048 + 16];  // +16 u32 zero pad for lr>=4 reads
  __shared__ float gates[1536];             // 6 waves x 256

  int bid = blockIdx.x;
  int d = bid >> 6, wl = bid & 63;
  int tid = threadIdx.x;
  int wave = tid >> 6, lane = tid & 63;
  int nt = wave % 3, kh = wave / 3;      // N-tile, K-half
  int lr = lane & 15, kq = lane >> 4;

  // --- init: B fragments direct global -> registers (one-time) ---
  short8 breg[16];
  {
    int c = nt * 16 + lr; if (c > 39) c = 39;   // cols 40-47 unused
    int g = c >> 3, jj = c & 7;
    int gcol = g * 512 + wl * 8 + jj;
    const unsigned short* wsrc = WhT + (long long)gcol * 1024 + kh * 512 + kq * 8;
#pragma unroll
    for (int kk = 0; kk < 16; kk++)
      breg[kk] = *(const short8*)(wsrc + kk * 32);
  }
  for (int i = tid; i < 2064; i += 384) Hl32[i] = 0u;
  __syncthreads();

  unsigned long long* Hme = Hbuf64 + d * 4096;  // [2][2048]
  unsigned int* Sme = Sent + d * 64;
  float c_r = 0.f, c_i = 0.f;
  int er = lane >> 3, ej = lane & 7;  // producer (row, col) when wave0, lane<32
  int np = (tid < 128) ? 6 : 5;       // bulk chunks per thread (384*5+128=2048)

  for (int t = 0; t < 512; t++) {
    float xg[5];
    if (wave == 0 && lane < 32) {  // issue early; latency hides under poll/GEMM
      const unsigned short* xp =
          Xperm + (((long long)(t * 64 + wl)) * 32 + (4 * d + er)) * 40;
#pragma unroll
      for (int g = 0; g < 5; g++) xg[g] = bf2f(xp[g * 8 + ej]);
    }

    if (t > 0) {
      // cheap sentinel poll: 64 sentinels, 1 load/lane/pass, every wave
      while (true) {
        unsigned sv = __hip_atomic_load(Sme + lane, __ATOMIC_RELAXED,
                                        __HIP_MEMORY_SCOPE_AGENT);
        if (__all(sv >= (unsigned)t)) break;
        __builtin_amdgcn_s_sleep(1);
      }
      // one bulk tagged read + stage (identity layout)
      const unsigned long long* hb = Hme + ((t - 1) & 1) * 2048;
      unsigned long long v[6];
#pragma unroll
      for (int p = 0; p < 6; p++)
        if (p < np)
          v[p] = __hip_atomic_load(hb + tid + p * 384, __ATOMIC_RELAXED,
                                   __HIP_MEMORY_SCOPE_AGENT);
#pragma unroll
      for (int p = 0; p < 6; p++)
        if (p < np) {
          while ((unsigned)(v[p] >> 32) != (unsigned)t)  // paranoia; ~never
            v[p] = __hip_atomic_load(hb + tid + p * 384, __ATOMIC_RELAXED,
                                     __HIP_MEMORY_SCOPE_AGENT);
          Hl32[tid + p * 384] = (unsigned)v[p];
        }
    }
    __syncthreads(); // B1: Hl staged

    // GEMM: A 16(4 real)x1024 @ Wh-slice; B in registers; split nt x kh.
    f32x4 acc0 = {0.f, 0.f, 0.f, 0.f};
    f32x4 acc1 = {0.f, 0.f, 0.f, 0.f};
#pragma unroll
    for (int kk = 0; kk < 8; kk++) {
      int ka = kh * 16 + kk;
      const unsigned int* ap = (lr < 4) ? (Hl32 + ((ka * 4 + kq) * 4 + lr) * 4)
                                        : (Hl32 + 2048);
      short8 a = *(const short8*)ap;
      acc0 = __builtin_amdgcn_mfma_f32_16x16x32_bf16(a, breg[kk], acc0, 0, 0, 0);
    }
#pragma unroll
    for (int kk = 8; kk < 16; kk++) {
      int ka = kh * 16 + kk;
      const unsigned int* ap = (lr < 4) ? (Hl32 + ((ka * 4 + kq) * 4 + lr) * 4)
                                        : (Hl32 + 2048);
      short8 a = *(const short8*)ap;
      acc1 = __builtin_amdgcn_mfma_f32_16x16x32_bf16(a, breg[kk], acc1, 0, 0, 0);
    }
    {
      f32x4 as = acc0 + acc1;
      int r0 = kq * 4;
#pragma unroll
      for (int r = 0; r < 4; r++)
        gates[wave * 256 + (r0 + r) * 16 + lr] = as[r];
    }
    __syncthreads(); // B2: gates write -> read

    if (wave == 0) {
      float hr = 0.f, hi = 0.f;
      if (lane < 32) {
        float gv[5];
#pragma unroll
        for (int g = 0; g < 5; g++) {
          int c = g * 8 + ej, tn = c >> 4, cw = c & 15;
          gv[g] = gates[tn * 256 + er * 16 + cw] +
                  gates[(3 + tn) * 256 + er * 16 + cw] + xg[g];
        }
        float ig = 1.f / (1.f + __expf(-gv[0]));
        float fg = 1.f / (1.f + __expf(-gv[1]));
        float og = 1.f / (1.f + __expf(-gv[2]));
        float crp = gv[3], cip = gv[4];
        float mag = fmaxf(sqrtf(crp * crp + cip * cip + 1e-14f), 1e-8f);
        float e1 = __expf(-2.f * mag);
        float s1 = (1.f - e1) * __frcp_rn((1.f + e1) * mag);
        c_r = fg * c_r + ig * (crp * s1);
        c_i = fg * c_i + ig * (cip * s1);
        float mag2 = fmaxf(sqrtf(c_r * c_r + c_i * c_i + 1e-14f), 1e-8f);
        float e2 = __expf(-2.f * mag2);
        float s2 = (1.f - e2) * __frcp_rn((1.f + e2) * mag2);
        hr = og * (c_r * s2);
        hi = og * (c_i * s2);
        // tagged data chunk (one per lane)
        int j = wl * 8 + ej;
        int ci = (j >> 2) * 16 + er * 4 + (j & 3);
        unsigned hv = (unsigned)f2bf(hr) | ((unsigned)f2bf(hi) << 16);
        __hip_atomic_store(Hme + (t & 1) * 2048 + ci,
                           ((unsigned long long)(t + 1) << 32) | hv,
                           __ATOMIC_RELAXED, __HIP_MEMORY_SCOPE_AGENT);
      }
      // drain THIS WAVE's data stores, then publish sentinel
      asm volatile("s_waitcnt vmcnt(0)" ::: "memory");
      if (lane == 0)
        __hip_atomic_store(Sme + wl, (unsigned)(t + 1),
                           __ATOMIC_RELAXED, __HIP_MEMORY_SCOPE_AGENT);
      if (lane < 32) {
        // shadow HBM output stores (overlap next step's poll)
        int j = wl * 8 + ej;
        int b = 4 * d + er;
        out[(long long)b * 262144 + t * 512 + j] = hr;
        out[8388608ll + (long long)b * 262144 + t * 512 + j] = hi;
        if (t == 511) {
          out[16777216ll + b * 512 + j] = hr;
          out[16793600ll + b * 512 + j] = hi;
          out[16809984ll + b * 512 + j] = c_r;
          out[16826368ll + b * 512 + j] = c_i;
        }
      }
    }
    // waves 1-5 proceed straight to next step's sentinel poll
  }
}

extern "C" void kernel_launch(void* const* d_in, const int* in_sizes, int n_in,
                              void* d_out, int out_size, void* d_ws, size_t ws_size,
                              hipStream_t stream) {
  const float* zr = (const float*)d_in[0];
  const float* zi = (const float*)d_in[1];
  // input group bases: i=2, f=8, c=14, o=20; within: WzR,WzI,WhR,WhI,bR,bI
  const int gi = 2, gf = 8, gc = 14, go = 20;
  PackArgs pa;
  const int gbase[5] = {gi, gf, go, gc, gc}; // internal g: 0=i,1=f,2=o,3=cr,4=ci
  for (int g = 0; g < 5; g++) {
    int b = gbase[g];
    if (g < 4) {
      pa.zlo[g] = (const float*)d_in[b + 0];
      pa.zhi[g] = (const float*)d_in[b + 1];
      pa.hlo[g] = (const float*)d_in[b + 2];
      pa.hhi[g] = (const float*)d_in[b + 3];
    } else { // ci: "lo" (real-mult) uses imag weight (+), "hi" (imag-mult) uses real weight (+)
      pa.zlo[g] = (const float*)d_in[b + 1];
      pa.zhi[g] = (const float*)d_in[b + 0];
      pa.hlo[g] = (const float*)d_in[b + 3];
      pa.hhi[g] = (const float*)d_in[b + 2];
    }
  }
  pa.bias[0] = (const float*)d_in[gi + 4];
  pa.bias[1] = (const float*)d_in[gf + 4];
  pa.bias[2] = (const float*)d_in[go + 4];
  pa.bias[3] = (const float*)d_in[gc + 4];
  pa.bias[4] = (const float*)d_in[gc + 5];

  char* ws = (char*)d_ws;
  unsigned short* WzT = (unsigned short*)(ws + OFF_WZT);
  unsigned short* WhT = (unsigned short*)(ws + OFF_WHT);
  float* bias = (float*)(ws + OFF_BIAS);
  unsigned short* Xperm = (unsigned short*)(ws + OFF_XPERM);
  unsigned long long* Hbuf64 = (unsigned long long*)(ws + OFF_HBUF);
  unsigned int* Sent = (unsigned int*)(ws + OFF_SENT);

  pack_kernel<<<2048, 256, 0, stream>>>(pa, WzT, WhT, bias, Hbuf64, Sent);
  phase1_kernel<<<10240, 256, 0, stream>>>(zr, zi, WzT, bias, Xperm);
  recur_kernel<<<NWG, 384, 0, stream>>>(WhT, Xperm, Hbuf64, Sent, (float*)d_out);
}

// Round 10
// 3820.776 us; speedup vs baseline: 1.4141x; 1.4141x over previous
//
#include <hip/hip_runtime.h>

// ComplexLSTM: B=32,S=512,I=512,H=512
// ws layout (bytes)
#define OFF_WZT   0ull
#define OFF_WHT   5242880ull
#define OFF_BIAS  10485760ull
#define OFF_XPERM 10496000ull
#define OFF_HBUF  94382080ull   // 4 domains x 2 bufs x 4096 u64 = 262144 B
#define NWG 256

typedef __attribute__((ext_vector_type(8))) short short8;
typedef __attribute__((ext_vector_type(4))) float f32x4;

__device__ __forceinline__ unsigned short f2bf(float f) {
  unsigned int u = __float_as_uint(f);
  u += 0x7fffu + ((u >> 16) & 1u);
  return (unsigned short)(u >> 16);
}
__device__ __forceinline__ float bf2f(unsigned short h) {
  return __uint_as_float(((unsigned int)h) << 16);
}

struct PackArgs {
  const float* zlo[5]; const float* zhi[5];
  const float* hlo[5]; const float* hhi[5];
  const float* bias[5];
};

// WzT[c][k]: k<512 -> z_r coeff (col k), k>=512 -> z_i coeff.
// WhT[c][k]: K interleaved: k=2*kk+ri, ri=0 -> h_r[kk] coeff, ri=1 -> h_i[kk] coeff.
// c = g*512+h (g: 0=i,1=f,2=o,3=cr,4=ci)
__global__ void pack_kernel(PackArgs args, unsigned short* __restrict__ WzT,
                            unsigned short* __restrict__ WhT,
                            float* __restrict__ bias_out,
                            unsigned long long* __restrict__ Hbuf64) {
  const long long total = 2ll * 2621440ll;
  long long stride = (long long)gridDim.x * blockDim.x;
  for (long long gid = (long long)blockIdx.x * blockDim.x + threadIdx.x; gid < total; gid += stride) {
    int sel = (int)(gid >= 2621440ll);
    int e = (int)(gid - (long long)sel * 2621440ll);
    int c = e >> 10, k = e & 1023;
    int g = c >> 9, h = c & 511;
    float v;
    if (sel) { // WhT interleaved
      int kk = k >> 1, ri = k & 1;
      const float* src = ri ? args.hhi[g] : args.hlo[g];
      float sgn = (!ri || g == 4) ? 1.f : -1.f;
      v = sgn * src[kk * 512 + h];
    } else {   // WzT block layout
      int kk = k & 511;
      const float* src = (k < 512) ? args.zlo[g] : args.zhi[g];
      float sgn = (k < 512 || g == 4) ? 1.f : -1.f;
      v = sgn * src[kk * 512 + h];
    }
    (sel ? WhT : WzT)[(long long)c * 1024 + k] = f2bf(v);
  }
  int gid0 = blockIdx.x * blockDim.x + threadIdx.x;
  if (gid0 < 2560) { int g = gid0 >> 9; bias_out[gid0] = args.bias[g][gid0 & 511]; }
  if (gid0 < 32768) Hbuf64[gid0] = 0ull; // clear all tags (replay safety)
}

// Phase 1: X = [z_r|z_i](16384x1024) @ WzT^T + bias -> bf16, permuted to [t][wg][b][40]
__global__ __launch_bounds__(256) void phase1_kernel(
    const float* __restrict__ zr, const float* __restrict__ zi,
    const unsigned short* __restrict__ WzT, const float* __restrict__ bias,
    unsigned short* __restrict__ Xperm) {
  __shared__ unsigned short Al[64 * 40];
  __shared__ unsigned short Bl[64 * 40];
  int bid = blockIdx.x;
  int bm = bid / 40, bn = bid % 40;
  int tid = threadIdx.x;
  int wave = tid >> 6, lane = tid & 63;
  int mq = wave >> 1, nq = wave & 1;
  int lr = lane & 15, lkb = (lane >> 4) * 8;
  int srow = tid >> 2, sq = tid & 3;

  f32x4 acc[2][2];
#pragma unroll
  for (int i0 = 0; i0 < 2; i0++)
#pragma unroll
    for (int j0 = 0; j0 < 2; j0++) acc[i0][j0] = (f32x4){0.f, 0.f, 0.f, 0.f};

  for (int kb = 0; kb < 32; kb++) {
    int gk = kb * 32 + sq * 8;
    const float* srcp = (gk < 512) ? (zr + (long long)(bm * 64 + srow) * 512 + gk)
                                   : (zi + (long long)(bm * 64 + srow) * 512 + (gk - 512));
    float4 f0 = *(const float4*)srcp;
    float4 f1 = *(const float4*)(srcp + 4);
    uint4 p;
    p.x = (unsigned)f2bf(f0.x) | ((unsigned)f2bf(f0.y) << 16);
    p.y = (unsigned)f2bf(f0.z) | ((unsigned)f2bf(f0.w) << 16);
    p.z = (unsigned)f2bf(f1.x) | ((unsigned)f2bf(f1.y) << 16);
    p.w = (unsigned)f2bf(f1.z) | ((unsigned)f2bf(f1.w) << 16);
    *(uint4*)(&Al[srow * 40 + sq * 8]) = p;
    const unsigned short* bsrc = WzT + (long long)(bn * 64 + srow) * 1024 + kb * 32 + sq * 8;
    *(uint4*)(&Bl[srow * 40 + sq * 8]) = *(const uint4*)bsrc;
    __syncthreads();
    short8 a0 = *(const short8*)(&Al[(mq * 32 + 0 + lr) * 40 + lkb]);
    short8 a1 = *(const short8*)(&Al[(mq * 32 + 16 + lr) * 40 + lkb]);
    short8 b0 = *(const short8*)(&Bl[(nq * 32 + 0 + lr) * 40 + lkb]);
    short8 b1 = *(const short8*)(&Bl[(nq * 32 + 16 + lr) * 40 + lkb]);
    acc[0][0] = __builtin_amdgcn_mfma_f32_16x16x32_bf16(a0, b0, acc[0][0], 0, 0, 0);
    acc[0][1] = __builtin_amdgcn_mfma_f32_16x16x32_bf16(a0, b1, acc[0][1], 0, 0, 0);
    acc[1][0] = __builtin_amdgcn_mfma_f32_16x16x32_bf16(a1, b0, acc[1][0], 0, 0, 0);
    acc[1][1] = __builtin_amdgcn_mfma_f32_16x16x32_bf16(a1, b1, acc[1][1], 0, 0, 0);
    __syncthreads();
  }
#pragma unroll
  for (int mt = 0; mt < 2; mt++)
#pragma unroll
    for (int nt = 0; nt < 2; nt++) {
      int C = bn * 64 + nq * 32 + nt * 16 + lr;
      float bv = bias[C];
      int g = C >> 9, h = C & 511;
      int wgc = h >> 3, jj = h & 7;
#pragma unroll
      for (int r = 0; r < 4; r++) {
        int R = bm * 64 + mq * 32 + mt * 16 + (lane >> 4) * 4 + r;
        int bb = R >> 9, tt = R & 511;
        float v = acc[mt][nt][r] + bv;
        Xperm[(((long long)(tt * 64 + wgc)) * 32 + bb) * 40 + g * 8 + jj] = f2bf(v);
      }
    }
}

// Phase 2: 4 independent sync domains (8 batch rows each) x 64 WGs.
// WG (d, wl) owns hidden cols [8*wl, 8*wl+8) of all 5 gates for batch rows [8d, 8d+8).
// h-broadcast: tagged u64 chunks: (tag = t+1)<<32 | (bf16 h_r | h_i<<16).
// chunk idx c for (row r, col j): c = ((j>>2)*8 + r)*4 + (j&3)  (fragment-major).
// No flags, no fences, no drains: the staging poll IS the sync.
// Poll assignment is CONTIGUOUS per thread (<=2 LLC lines/thread/pass, producer affinity).
__global__ __launch_bounds__(384) void recur_kernel(
    const unsigned short* __restrict__ WhT,
    const unsigned short* __restrict__ Xperm,
    unsigned long long* __restrict__ Hbuf64,
    float* __restrict__ out) {
  extern __shared__ unsigned short lds[];
  unsigned short* Wl = lds;                            // [40][1032] bf16 (82560 B)
  unsigned int* Hl32 = (unsigned int*)(lds + 41280);   // 8192 u32 (32768 B), frag-major
  float* gates = (float*)((char*)(lds + 41280) + 32768); // [6][16][16] f32 (6144 B)

  int bid = blockIdx.x;
  int d = bid >> 6, wl = bid & 63;
  int tid = threadIdx.x;
  int wave = tid >> 6, lane = tid & 63;
  int nt = wave % 3, kh = wave / 3;      // N-tile, K-half
  int lr = lane & 15, kq = lane >> 4;

  // one-time: stage this WG's 40-column Wh slice into LDS
  for (int idx = tid; idx < 5120; idx += 384) {
    int r = idx >> 7, ch = idx & 127;
    int gcol = (r >> 3) * 512 + wl * 8 + (r & 7);
    uint4 v = *(const uint4*)(WhT + (long long)gcol * 1024 + ch * 8);
    *(uint4*)(&Wl[r * 1032 + ch * 8]) = v;
  }
  // zero Hl (rows 8-15 of each fragment group stay zero forever -> M=8 padding)
  {
    uint4 z = {0u, 0u, 0u, 0u};
    for (int idx = tid; idx < 2048; idx += 384) ((uint4*)Hl32)[idx] = z;
  }

  unsigned long long* Hme = Hbuf64 + d * 8192;
  // contiguous chunk ranges: threads 0-255 take 11, threads 256-383 take 10 (4096 total)
  const int nch = (tid < 256) ? 11 : 10;
  const int cbase = (tid < 256) ? tid * 11 : 2816 + (tid - 256) * 10;
  const unsigned need = (tid < 256) ? 0x7FFu : 0x3FFu;

  float c_r = 0.f, c_i = 0.f;
  int er = tid >> 3, ej = tid & 7; // elementwise (row, col) when tid < 64

  for (int t = 0; t < 512; t++) {
    float xg[5];
    if (tid < 64) { // prefetch X pre-activations (latency hides under poll)
      const unsigned short* xp = Xperm + (((long long)(t * 64 + wl)) * 32 + (8 * d + er)) * 40;
#pragma unroll
      for (int g = 0; g < 5; g++) xg[g] = bf2f(xp[g * 8 + ej]);
    }

    if (t > 0) {
      const unsigned long long* hb = Hme + ((t - 1) & 1) * 4096;
      unsigned long long v[11];
      unsigned got = 0;
      while (true) {
#pragma unroll
        for (int p = 0; p < 11; p++)
          if (p < nch && !(got & (1u << p)))
            v[p] = __hip_atomic_load(hb + cbase + p, __ATOMIC_RELAXED,
                                     __HIP_MEMORY_SCOPE_AGENT);
        unsigned g2 = got;
#pragma unroll
        for (int p = 0; p < 11; p++)
          if (p < nch && !(got & (1u << p)) && (unsigned)(v[p] >> 32) == (unsigned)t)
            g2 |= 1u << p;
        got = g2;
        if (got == need) break;
        __builtin_amdgcn_s_sleep(1);
      }
#pragma unroll
      for (int p = 0; p < 11; p++)
        if (p < nch) {
          int c = cbase + p;
          Hl32[((c >> 5) * 16 + ((c >> 2) & 7)) * 4 + (c & 3)] = (unsigned)v[p];
        }
    }
    __syncthreads(); // B1: staging visible (also covers gates WAR, init zeros at t=0)

    // GEMM: A (16x1024, rows 8-15 zero) @ Wh-slice -> 16x48 (40 used), per wave:
    // N-tile nt, K-half kh (512 K each), two 8-deep dependent chains.
    f32x4 acc0 = {0.f, 0.f, 0.f, 0.f};
    f32x4 acc1 = {0.f, 0.f, 0.f, 0.f};
    const unsigned short* Hls = (const unsigned short*)Hl32;
#pragma unroll
    for (int kk = 0; kk < 8; kk++) {
      int ka = kh * 16 + kk;
      short8 a = *(const short8*)(Hls + (ka * 4 + kq) * 128 + lr * 8);
      short8 b = *(const short8*)(&Wl[(nt * 16 + lr) * 1032 + ka * 32 + kq * 8]);
      acc0 = __builtin_amdgcn_mfma_f32_16x16x32_bf16(a, b, acc0, 0, 0, 0);
    }
#pragma unroll
    for (int kk = 8; kk < 16; kk++) {
      int ka = kh * 16 + kk;
      short8 a = *(const short8*)(Hls + (ka * 4 + kq) * 128 + lr * 8);
      short8 b = *(const short8*)(&Wl[(nt * 16 + lr) * 1032 + ka * 32 + kq * 8]);
      acc1 = __builtin_amdgcn_mfma_f32_16x16x32_bf16(a, b, acc1, 0, 0, 0);
    }
    {
      int r0 = (lane >> 4) * 4;
#pragma unroll
      for (int r = 0; r < 4; r++)
        gates[wave * 256 + (r0 + r) * 16 + lr] = acc0[r] + acc1[r];
    }
    __syncthreads(); // B2: gates write -> read

    if (tid < 64) {
      float gv[5];
#pragma unroll
      for (int g = 0; g < 5; g++) {
        int c = g * 8 + ej, tn = c >> 4, cw = c & 15;
        gv[g] = gates[tn * 256 + er * 16 + cw] + gates[(3 + tn) * 256 + er * 16 + cw] + xg[g];
      }
      float ig = 1.f / (1.f + __expf(-gv[0]));
      float fg = 1.f / (1.f + __expf(-gv[1]));
      float og = 1.f / (1.f + __expf(-gv[2]));
      float crp = gv[3], cip = gv[4];
      float mag = fmaxf(sqrtf(crp * crp + cip * cip + 1e-14f), 1e-8f);
      float e1 = __expf(-2.f * mag);
      float s1 = (1.f - e1) * __frcp_rn((1.f + e1) * mag);
      c_r = fg * c_r + ig * (crp * s1);
      c_i = fg * c_i + ig * (cip * s1);
      float mag2 = fmaxf(sqrtf(c_r * c_r + c_i * c_i + 1e-14f), 1e-8f);
      float e2 = __expf(-2.f * mag2);
      float s2 = (1.f - e2) * __frcp_rn((1.f + e2) * mag2);
      float hr = og * (c_r * s2);
      float hi = og * (c_i * s2);
      // tagged broadcast chunk: single atomic u64, no drain/flag/fence needed
      int j = wl * 8 + ej;
      int cidx = ((j >> 2) * 8 + er) * 4 + (j & 3);
      unsigned hv = (unsigned)f2bf(hr) | ((unsigned)f2bf(hi) << 16);
      __hip_atomic_store(Hme + (t & 1) * 4096 + cidx,
                         ((unsigned long long)(t + 1) << 32) | hv,
                         __ATOMIC_RELAXED, __HIP_MEMORY_SCOPE_AGENT);
      // shadow HBM output stores (overlap next step's poll)
      int b = 8 * d + er;
      out[(long long)b * 262144 + t * 512 + j] = hr;
      out[8388608ll + (long long)b * 262144 + t * 512 + j] = hi;
      if (t == 511) {
        out[16777216ll + b * 512 + j] = hr;
        out[16793600ll + b * 512 + j] = hi;
        out[16809984ll + b * 512 + j] = c_r;
        out[16826368ll + b * 512 + j] = c_i;
      }
    }
    // waves 1-5 proceed directly to next step's poll (overlaps wave0 elementwise)
  }
}

extern "C" void kernel_launch(void* const* d_in, const int* in_sizes, int n_in,
                              void* d_out, int out_size, void* d_ws, size_t ws_size,
                              hipStream_t stream) {
  const float* zr = (const float*)d_in[0];
  const float* zi = (const float*)d_in[1];
  // input group bases: i=2, f=8, c=14, o=20; within: WzR,WzI,WhR,WhI,bR,bI
  const int gi = 2, gf = 8, gc = 14, go = 20;
  PackArgs pa;
  const int gbase[5] = {gi, gf, go, gc, gc}; // internal g: 0=i,1=f,2=o,3=cr,4=ci
  for (int g = 0; g < 5; g++) {
    int b = gbase[g];
    if (g < 4) {
      pa.zlo[g] = (const float*)d_in[b + 0];
      pa.zhi[g] = (const float*)d_in[b + 1];
      pa.hlo[g] = (const float*)d_in[b + 2];
      pa.hhi[g] = (const float*)d_in[b + 3];
    } else { // ci: "lo" (real-mult) uses imag weight (+), "hi" (imag-mult) uses real weight (+)
      pa.zlo[g] = (const float*)d_in[b + 1];
      pa.zhi[g] = (const float*)d_in[b + 0];
      pa.hlo[g] = (const float*)d_in[b + 3];
      pa.hhi[g] = (const float*)d_in[b + 2];
    }
  }
  pa.bias[0] = (const float*)d_in[gi + 4];
  pa.bias[1] = (const float*)d_in[gf + 4];
  pa.bias[2] = (const float*)d_in[go + 4];
  pa.bias[3] = (const float*)d_in[gc + 4];
  pa.bias[4] = (const float*)d_in[gc + 5];

  char* ws = (char*)d_ws;
  unsigned short* WzT = (unsigned short*)(ws + OFF_WZT);
  unsigned short* WhT = (unsigned short*)(ws + OFF_WHT);
  float* bias = (float*)(ws + OFF_BIAS);
  unsigned short* Xperm = (unsigned short*)(ws + OFF_XPERM);
  unsigned long long* Hbuf64 = (unsigned long long*)(ws + OFF_HBUF);

  pack_kernel<<<2048, 256, 0, stream>>>(pa, WzT, WhT, bias, Hbuf64);
  phase1_kernel<<<10240, 256, 0, stream>>>(zr, zi, WzT, bias, Xperm);

  const int ldsBytes = 82560 + 32768 + 6144; // 121472
  (void)hipFuncSetAttribute((const void*)recur_kernel,
                            hipFuncAttributeMaxDynamicSharedMemorySize, ldsBytes);
  recur_kernel<<<NWG, 384, ldsBytes, stream>>>(WhT, Xperm, Hbuf64, (float*)d_out);
}

// Round 11
// 1797.613 us; speedup vs baseline: 3.0056x; 2.1255x over previous
//
#include <hip/hip_runtime.h>

// ComplexLSTM: B=32,S=512,I=512,H=512
// ws layout (bytes)
#define OFF_WZT   0ull
#define OFF_WHT   5242880ull
#define OFF_BIAS  10485760ull
#define OFF_XPERM 10496000ull
#define OFF_HBUF  94382080ull   // 4 domains x 2 bufs x 4096 u64 = 262144 B
#define NWG 256

typedef __attribute__((ext_vector_type(8))) short short8;
typedef __attribute__((ext_vector_type(4))) float f32x4;

__device__ __forceinline__ unsigned short f2bf(float f) {
  unsigned int u = __float_as_uint(f);
  u += 0x7fffu + ((u >> 16) & 1u);
  return (unsigned short)(u >> 16);
}
__device__ __forceinline__ float bf2f(unsigned short h) {
  return __uint_as_float(((unsigned int)h) << 16);
}

struct PackArgs {
  const float* zlo[5]; const float* zhi[5];
  const float* hlo[5]; const float* hhi[5];
  const float* bias[5];
};

// WzT[c][k]: k<512 -> z_r coeff (col k), k>=512 -> z_i coeff.
// WhT[c][k]: K interleaved: k=2*kk+ri, ri=0 -> h_r[kk] coeff, ri=1 -> h_i[kk] coeff.
// c = g*512+h (g: 0=i,1=f,2=o,3=cr,4=ci)
__global__ void pack_kernel(PackArgs args, unsigned short* __restrict__ WzT,
                            unsigned short* __restrict__ WhT,
                            float* __restrict__ bias_out,
                            unsigned long long* __restrict__ Hbuf64) {
  const long long total = 2ll * 2621440ll;
  long long stride = (long long)gridDim.x * blockDim.x;
  for (long long gid = (long long)blockIdx.x * blockDim.x + threadIdx.x; gid < total; gid += stride) {
    int sel = (int)(gid >= 2621440ll);
    int e = (int)(gid - (long long)sel * 2621440ll);
    int c = e >> 10, k = e & 1023;
    int g = c >> 9, h = c & 511;
    float v;
    if (sel) { // WhT interleaved
      int kk = k >> 1, ri = k & 1;
      const float* src = ri ? args.hhi[g] : args.hlo[g];
      float sgn = (!ri || g == 4) ? 1.f : -1.f;
      v = sgn * src[kk * 512 + h];
    } else {   // WzT block layout
      int kk = k & 511;
      const float* src = (k < 512) ? args.zlo[g] : args.zhi[g];
      float sgn = (k < 512 || g == 4) ? 1.f : -1.f;
      v = sgn * src[kk * 512 + h];
    }
    (sel ? WhT : WzT)[(long long)c * 1024 + k] = f2bf(v);
  }
  int gid0 = blockIdx.x * blockDim.x + threadIdx.x;
  if (gid0 < 2560) { int g = gid0 >> 9; bias_out[gid0] = args.bias[g][gid0 & 511]; }
  if (gid0 < 32768) Hbuf64[gid0] = 0ull; // clear all tags (replay safety)
}

// Phase 1: X = [z_r|z_i](16384x1024) @ WzT^T + bias -> bf16, permuted to [t][wg][b][40]
__global__ __launch_bounds__(256) void phase1_kernel(
    const float* __restrict__ zr, const float* __restrict__ zi,
    const unsigned short* __restrict__ WzT, const float* __restrict__ bias,
    unsigned short* __restrict__ Xperm) {
  __shared__ unsigned short Al[64 * 40];
  __shared__ unsigned short Bl[64 * 40];
  int bid = blockIdx.x;
  int bm = bid / 40, bn = bid % 40;
  int tid = threadIdx.x;
  int wave = tid >> 6, lane = tid & 63;
  int mq = wave >> 1, nq = wave & 1;
  int lr = lane & 15, lkb = (lane >> 4) * 8;
  int srow = tid >> 2, sq = tid & 3;

  f32x4 acc[2][2];
#pragma unroll
  for (int i0 = 0; i0 < 2; i0++)
#pragma unroll
    for (int j0 = 0; j0 < 2; j0++) acc[i0][j0] = (f32x4){0.f, 0.f, 0.f, 0.f};

  for (int kb = 0; kb < 32; kb++) {
    int gk = kb * 32 + sq * 8;
    const float* srcp = (gk < 512) ? (zr + (long long)(bm * 64 + srow) * 512 + gk)
                                   : (zi + (long long)(bm * 64 + srow) * 512 + (gk - 512));
    float4 f0 = *(const float4*)srcp;
    float4 f1 = *(const float4*)(srcp + 4);
    uint4 p;
    p.x = (unsigned)f2bf(f0.x) | ((unsigned)f2bf(f0.y) << 16);
    p.y = (unsigned)f2bf(f0.z) | ((unsigned)f2bf(f0.w) << 16);
    p.z = (unsigned)f2bf(f1.x) | ((unsigned)f2bf(f1.y) << 16);
    p.w = (unsigned)f2bf(f1.z) | ((unsigned)f2bf(f1.w) << 16);
    *(uint4*)(&Al[srow * 40 + sq * 8]) = p;
    const unsigned short* bsrc = WzT + (long long)(bn * 64 + srow) * 1024 + kb * 32 + sq * 8;
    *(uint4*)(&Bl[srow * 40 + sq * 8]) = *(const uint4*)bsrc;
    __syncthreads();
    short8 a0 = *(const short8*)(&Al[(mq * 32 + 0 + lr) * 40 + lkb]);
    short8 a1 = *(const short8*)(&Al[(mq * 32 + 16 + lr) * 40 + lkb]);
    short8 b0 = *(const short8*)(&Bl[(nq * 32 + 0 + lr) * 40 + lkb]);
    short8 b1 = *(const short8*)(&Bl[(nq * 32 + 16 + lr) * 40 + lkb]);
    acc[0][0] = __builtin_amdgcn_mfma_f32_16x16x32_bf16(a0, b0, acc[0][0], 0, 0, 0);
    acc[0][1] = __builtin_amdgcn_mfma_f32_16x16x32_bf16(a0, b1, acc[0][1], 0, 0, 0);
    acc[1][0] = __builtin_amdgcn_mfma_f32_16x16x32_bf16(a1, b0, acc[1][0], 0, 0, 0);
    acc[1][1] = __builtin_amdgcn_mfma_f32_16x16x32_bf16(a1, b1, acc[1][1], 0, 0, 0);
    __syncthreads();
  }
#pragma unroll
  for (int mt = 0; mt < 2; mt++)
#pragma unroll
    for (int nt = 0; nt < 2; nt++) {
      int C = bn * 64 + nq * 32 + nt * 16 + lr;
      float bv = bias[C];
      int g = C >> 9, h = C & 511;
      int wgc = h >> 3, jj = h & 7;
#pragma unroll
      for (int r = 0; r < 4; r++) {
        int R = bm * 64 + mq * 32 + mt * 16 + (lane >> 4) * 4 + r;
        int bb = R >> 9, tt = R & 511;
        float v = acc[mt][nt][r] + bv;
        Xperm[(((long long)(tt * 64 + wgc)) * 32 + bb) * 40 + g * 8 + jj] = f2bf(v);
      }
    }
}

// Phase 2: 4 independent sync domains (8 batch rows each) x 64 WGs.
// WG (d, wl) owns hidden cols [8*wl, 8*wl+8) of all 5 gates for batch rows [8d, 8d+8).
// h-broadcast: tagged u64 chunks: (tag = t+1)<<32 | (bf16 h_r | h_i<<16).
// chunk idx c for (row r, col j): c = ((j>>2)*8 + r)*4 + (j&3)  (fragment-major).
// No flags, no fences, no drains: the staging poll IS the sync.
// Poll assignment STRIDED (hb + tid + p*384): each wave-wide load touches 64
// consecutive u64 -> 8 cache lines, fully coalesced (r10 taught us the hard way).
__global__ __launch_bounds__(384) void recur_kernel(
    const unsigned short* __restrict__ WhT,
    const unsigned short* __restrict__ Xperm,
    unsigned long long* __restrict__ Hbuf64,
    float* __restrict__ out) {
  extern __shared__ unsigned short lds[];
  unsigned short* Wl = lds;                            // [40][1032] bf16 (82560 B)
  unsigned int* Hl32 = (unsigned int*)(lds + 41280);   // 8192 u32 (32768 B), frag-major
  float* gates = (float*)((char*)(lds + 41280) + 32768); // [6][16][16] f32 (6144 B)

  int bid = blockIdx.x;
  int d = bid >> 6, wl = bid & 63;
  int tid = threadIdx.x;
  int wave = tid >> 6, lane = tid & 63;
  int nt = wave % 3, kh = wave / 3;      // N-tile, K-half
  int lr = lane & 15, kq = lane >> 4;

  // one-time: stage this WG's 40-column Wh slice into LDS
  for (int idx = tid; idx < 5120; idx += 384) {
    int r = idx >> 7, ch = idx & 127;
    int gcol = (r >> 3) * 512 + wl * 8 + (r & 7);
    uint4 v = *(const uint4*)(WhT + (long long)gcol * 1024 + ch * 8);
    *(uint4*)(&Wl[r * 1032 + ch * 8]) = v;
  }
  // zero Hl (rows 8-15 of each fragment group stay zero forever -> M=8 padding)
  {
    uint4 z = {0u, 0u, 0u, 0u};
    for (int idx = tid; idx < 2048; idx += 384) ((uint4*)Hl32)[idx] = z;
  }

  unsigned long long* Hme = Hbuf64 + d * 8192;
  const int nch = (tid < 256) ? 11 : 10;          // 4096 chunks / 384 threads
  const unsigned need = (tid < 256) ? 0x7FFu : 0x3FFu;

  float c_r = 0.f, c_i = 0.f;
  int er = tid >> 3, ej = tid & 7; // elementwise (row, col) when tid < 64

  for (int t = 0; t < 512; t++) {
    float xg[5];
    if (tid < 64) { // prefetch X pre-activations (latency hides under poll)
      const unsigned short* xp = Xperm + (((long long)(t * 64 + wl)) * 32 + (8 * d + er)) * 40;
#pragma unroll
      for (int g = 0; g < 5; g++) xg[g] = bf2f(xp[g * 8 + ej]);
    }

    if (t > 0) {
      const unsigned long long* hb = Hme + ((t - 1) & 1) * 4096;
      unsigned long long v[11];
      unsigned got = 0;
      while (true) {
#pragma unroll
        for (int p = 0; p < 11; p++)
          if (p < nch && !(got & (1u << p)))
            v[p] = __hip_atomic_load(hb + tid + p * 384, __ATOMIC_RELAXED,
                                     __HIP_MEMORY_SCOPE_AGENT);
        unsigned g2 = got;
#pragma unroll
        for (int p = 0; p < 11; p++)
          if (p < nch && !(got & (1u << p)) && (unsigned)(v[p] >> 32) == (unsigned)t)
            g2 |= 1u << p;
        got = g2;
        if (got == need) break;
        __builtin_amdgcn_s_sleep(1);
      }
#pragma unroll
      for (int p = 0; p < 11; p++)
        if (p < nch) {
          int c = tid + p * 384;
          Hl32[((c >> 5) * 16 + ((c >> 2) & 7)) * 4 + (c & 3)] = (unsigned)v[p];
        }
    }
    __syncthreads(); // B1: staging visible (also covers gates WAR, init zeros at t=0)

    // GEMM: A (16x1024, rows 8-15 zero) @ Wh-slice -> 16x48 (40 used), per wave:
    // N-tile nt, K-half kh (512 K each), two 8-deep dependent chains.
    f32x4 acc0 = {0.f, 0.f, 0.f, 0.f};
    f32x4 acc1 = {0.f, 0.f, 0.f, 0.f};
    const unsigned short* Hls = (const unsigned short*)Hl32;
#pragma unroll
    for (int kk = 0; kk < 8; kk++) {
      int ka = kh * 16 + kk;
      short8 a = *(const short8*)(Hls + (ka * 4 + kq) * 128 + lr * 8);
      short8 b = *(const short8*)(&Wl[(nt * 16 + lr) * 1032 + ka * 32 + kq * 8]);
      acc0 = __builtin_amdgcn_mfma_f32_16x16x32_bf16(a, b, acc0, 0, 0, 0);
    }
#pragma unroll
    for (int kk = 8; kk < 16; kk++) {
      int ka = kh * 16 + kk;
      short8 a = *(const short8*)(Hls + (ka * 4 + kq) * 128 + lr * 8);
      short8 b = *(const short8*)(&Wl[(nt * 16 + lr) * 1032 + ka * 32 + kq * 8]);
      acc1 = __builtin_amdgcn_mfma_f32_16x16x32_bf16(a, b, acc1, 0, 0, 0);
    }
    {
      int r0 = (lane >> 4) * 4;
#pragma unroll
      for (int r = 0; r < 4; r++)
        gates[wave * 256 + (r0 + r) * 16 + lr] = acc0[r] + acc1[r];
    }
    __syncthreads(); // B2: gates write -> read

    if (tid < 64) {
      float gv[5];
#pragma unroll
      for (int g = 0; g < 5; g++) {
        int c = g * 8 + ej, tn = c >> 4, cw = c & 15;
        gv[g] = gates[tn * 256 + er * 16 + cw] + gates[(3 + tn) * 256 + er * 16 + cw] + xg[g];
      }
      float ig = 1.f / (1.f + __expf(-gv[0]));
      float fg = 1.f / (1.f + __expf(-gv[1]));
      float og = 1.f / (1.f + __expf(-gv[2]));
      float crp = gv[3], cip = gv[4];
      float mag = fmaxf(sqrtf(crp * crp + cip * cip + 1e-14f), 1e-8f);
      float e1 = __expf(-2.f * mag);
      float s1 = (1.f - e1) * __frcp_rn((1.f + e1) * mag);
      c_r = fg * c_r + ig * (crp * s1);
      c_i = fg * c_i + ig * (cip * s1);
      float mag2 = fmaxf(sqrtf(c_r * c_r + c_i * c_i + 1e-14f), 1e-8f);
      float e2 = __expf(-2.f * mag2);
      float s2 = (1.f - e2) * __frcp_rn((1.f + e2) * mag2);
      float hr = og * (c_r * s2);
      float hi = og * (c_i * s2);
      // tagged broadcast chunk: single atomic u64, no drain/flag/fence needed
      int j = wl * 8 + ej;
      int cidx = ((j >> 2) * 8 + er) * 4 + (j & 3);
      unsigned hv = (unsigned)f2bf(hr) | ((unsigned)f2bf(hi) << 16);
      __hip_atomic_store(Hme + (t & 1) * 4096 + cidx,
                         ((unsigned long long)(t + 1) << 32) | hv,
                         __ATOMIC_RELAXED, __HIP_MEMORY_SCOPE_AGENT);
      // shadow HBM output stores (overlap next step's poll)
      int b = 8 * d + er;
      out[(long long)b * 262144 + t * 512 + j] = hr;
      out[8388608ll + (long long)b * 262144 + t * 512 + j] = hi;
      if (t == 511) {
        out[16777216ll + b * 512 + j] = hr;
        out[16793600ll + b * 512 + j] = hi;
        out[16809984ll + b * 512 + j] = c_r;
        out[16826368ll + b * 512 + j] = c_i;
      }
    }
    // waves 1-5 proceed directly to next step's poll (overlaps wave0 elementwise)
  }
}

extern "C" void kernel_launch(void* const* d_in, const int* in_sizes, int n_in,
                              void* d_out, int out_size, void* d_ws, size_t ws_size,
                              hipStream_t stream) {
  const float* zr = (const float*)d_in[0];
  const float* zi = (const float*)d_in[1];
  // input group bases: i=2, f=8, c=14, o=20; within: WzR,WzI,WhR,WhI,bR,bI
  const int gi = 2, gf = 8, gc = 14, go = 20;
  PackArgs pa;
  const int gbase[5] = {gi, gf, go, gc, gc}; // internal g: 0=i,1=f,2=o,3=cr,4=ci
  for (int g = 0; g < 5; g++) {
    int b = gbase[g];
    if (g < 4) {
      pa.zlo[g] = (const float*)d_in[b + 0];
      pa.zhi[g] = (const float*)d_in[b + 1];
      pa.hlo[g] = (const float*)d_in[b + 2];
      pa.hhi[g] = (const float*)d_in[b + 3];
    } else { // ci: "lo" (real-mult) uses imag weight (+), "hi" (imag-mult) uses real weight (+)
      pa.zlo[g] = (const float*)d_in[b + 1];
      pa.zhi[g] = (const float*)d_in[b + 0];
      pa.hlo[g] = (const float*)d_in[b + 3];
      pa.hhi[g] = (const float*)d_in[b + 2];
    }
  }
  pa.bias[0] = (const float*)d_in[gi + 4];
  pa.bias[1] = (const float*)d_in[gf + 4];
  pa.bias[2] = (const float*)d_in[go + 4];
  pa.bias[3] = (const float*)d_in[gc + 4];
  pa.bias[4] = (const float*)d_in[gc + 5];

  char* ws = (char*)d_ws;
  unsigned short* WzT = (unsigned short*)(ws + OFF_WZT);
  unsigned short* WhT = (unsigned short*)(ws + OFF_WHT);
  float* bias = (float*)(ws + OFF_BIAS);
  unsigned short* Xperm = (unsigned short*)(ws + OFF_XPERM);
  unsigned long long* Hbuf64 = (unsigned long long*)(ws + OFF_HBUF);

  pack_kernel<<<2048, 256, 0, stream>>>(pa, WzT, WhT, bias, Hbuf64);
  phase1_kernel<<<10240, 256, 0, stream>>>(zr, zi, WzT, bias, Xperm);

  const int ldsBytes = 82560 + 32768 + 6144; // 121472
  (void)hipFuncSetAttribute((const void*)recur_kernel,
                            hipFuncAttributeMaxDynamicSharedMemorySize, ldsBytes);
  recur_kernel<<<NWG, 384, ldsBytes, stream>>>(WhT, Xperm, Hbuf64, (float*)d_out);
}

// Round 12
// 1779.119 us; speedup vs baseline: 3.0368x; 1.0104x over previous
//
#include <hip/hip_runtime.h>

// ComplexLSTM: B=32,S=512,I=512,H=512
// ws layout (bytes)
#define OFF_WZT   0ull
#define OFF_WHT   5242880ull
#define OFF_BIAS  10485760ull
#define OFF_XPERM 10496000ull
#define OFF_HBUF  94382080ull   // 4 domains x 2 bufs x 4096 u64 = 262144 B
#define NWG 256

typedef __attribute__((ext_vector_type(8))) short short8;
typedef __attribute__((ext_vector_type(4))) float f32x4;

__device__ __forceinline__ unsigned short f2bf(float f) {
  unsigned int u = __float_as_uint(f);
  u += 0x7fffu + ((u >> 16) & 1u);
  return (unsigned short)(u >> 16);
}
__device__ __forceinline__ float bf2f(unsigned short h) {
  return __uint_as_float(((unsigned int)h) << 16);
}

struct PackArgs {
  const float* zlo[5]; const float* zhi[5];
  const float* hlo[5]; const float* hhi[5];
  const float* bias[5];
};

// WzT[c][k]: k<512 -> z_r coeff (col k), k>=512 -> z_i coeff.
// WhT[c][k]: K interleaved: k=2*kk+ri, ri=0 -> h_r[kk] coeff, ri=1 -> h_i[kk] coeff.
// c = g*512+h (g: 0=i,1=f,2=o,3=cr,4=ci)
__global__ void pack_kernel(PackArgs args, unsigned short* __restrict__ WzT,
                            unsigned short* __restrict__ WhT,
                            float* __restrict__ bias_out,
                            unsigned long long* __restrict__ Hbuf64) {
  const long long total = 2ll * 2621440ll;
  long long stride = (long long)gridDim.x * blockDim.x;
  for (long long gid = (long long)blockIdx.x * blockDim.x + threadIdx.x; gid < total; gid += stride) {
    int sel = (int)(gid >= 2621440ll);
    int e = (int)(gid - (long long)sel * 2621440ll);
    int c = e >> 10, k = e & 1023;
    int g = c >> 9, h = c & 511;
    float v;
    if (sel) { // WhT interleaved
      int kk = k >> 1, ri = k & 1;
      const float* src = ri ? args.hhi[g] : args.hlo[g];
      float sgn = (!ri || g == 4) ? 1.f : -1.f;
      v = sgn * src[kk * 512 + h];
    } else {   // WzT block layout
      int kk = k & 511;
      const float* src = (k < 512) ? args.zlo[g] : args.zhi[g];
      float sgn = (k < 512 || g == 4) ? 1.f : -1.f;
      v = sgn * src[kk * 512 + h];
    }
    (sel ? WhT : WzT)[(long long)c * 1024 + k] = f2bf(v);
  }
  int gid0 = blockIdx.x * blockDim.x + threadIdx.x;
  if (gid0 < 2560) { int g = gid0 >> 9; bias_out[gid0] = args.bias[g][gid0 & 511]; }
  if (gid0 < 32768) Hbuf64[gid0] = 0ull; // clear all tags (replay safety)
}

// Phase 1: X = [z_r|z_i](16384x1024) @ WzT^T + bias -> bf16, permuted to [t][wg][b][40]
// 128x64 tile per 256-thread block (4 waves, each 64 rows x 32 cols; 8 MFMA/K-step).
__global__ __launch_bounds__(256) void phase1_kernel(
    const float* __restrict__ zr, const float* __restrict__ zi,
    const unsigned short* __restrict__ WzT, const float* __restrict__ bias,
    unsigned short* __restrict__ Xperm) {
  __shared__ unsigned short Al[128 * 40];
  __shared__ unsigned short Bl[64 * 40];
  int bid = blockIdx.x;
  int bm = bid / 40, bn = bid % 40;
  int tid = threadIdx.x;
  int wave = tid >> 6, lane = tid & 63;
  int mq = wave >> 1, nq = wave & 1;
  int lr = lane & 15, lkb = (lane >> 4) * 8;
  int arow = tid >> 1, aq = tid & 1;   // A staging: 2 thr/row, 16 elems each
  int brow = tid >> 2, bq = tid & 3;   // B staging: 4 thr/row, 8 elems each

  f32x4 acc[4][2];
#pragma unroll
  for (int i0 = 0; i0 < 4; i0++)
#pragma unroll
    for (int j0 = 0; j0 < 2; j0++) acc[i0][j0] = (f32x4){0.f, 0.f, 0.f, 0.f};

  for (int kb = 0; kb < 32; kb++) {
    {
      int gk = kb * 32 + aq * 16;
      const float* srcp = (gk < 512)
          ? (zr + (long long)(bm * 128 + arow) * 512 + gk)
          : (zi + (long long)(bm * 128 + arow) * 512 + (gk - 512));
      float4 f0 = *(const float4*)srcp;
      float4 f1 = *(const float4*)(srcp + 4);
      float4 f2 = *(const float4*)(srcp + 8);
      float4 f3 = *(const float4*)(srcp + 12);
      uint4 p0, p1;
      p0.x = (unsigned)f2bf(f0.x) | ((unsigned)f2bf(f0.y) << 16);
      p0.y = (unsigned)f2bf(f0.z) | ((unsigned)f2bf(f0.w) << 16);
      p0.z = (unsigned)f2bf(f1.x) | ((unsigned)f2bf(f1.y) << 16);
      p0.w = (unsigned)f2bf(f1.z) | ((unsigned)f2bf(f1.w) << 16);
      p1.x = (unsigned)f2bf(f2.x) | ((unsigned)f2bf(f2.y) << 16);
      p1.y = (unsigned)f2bf(f2.z) | ((unsigned)f2bf(f2.w) << 16);
      p1.z = (unsigned)f2bf(f3.x) | ((unsigned)f2bf(f3.y) << 16);
      p1.w = (unsigned)f2bf(f3.z) | ((unsigned)f2bf(f3.w) << 16);
      *(uint4*)(&Al[arow * 40 + aq * 16]) = p0;
      *(uint4*)(&Al[arow * 40 + aq * 16 + 8]) = p1;
    }
    {
      const unsigned short* bsrc = WzT + (long long)(bn * 64 + brow) * 1024 + kb * 32 + bq * 8;
      *(uint4*)(&Bl[brow * 40 + bq * 8]) = *(const uint4*)bsrc;
    }
    __syncthreads();
    short8 b0 = *(const short8*)(&Bl[(nq * 32 + 0 + lr) * 40 + lkb]);
    short8 b1 = *(const short8*)(&Bl[(nq * 32 + 16 + lr) * 40 + lkb]);
#pragma unroll
    for (int mt = 0; mt < 4; mt++) {
      short8 a = *(const short8*)(&Al[(mq * 64 + mt * 16 + lr) * 40 + lkb]);
      acc[mt][0] = __builtin_amdgcn_mfma_f32_16x16x32_bf16(a, b0, acc[mt][0], 0, 0, 0);
      acc[mt][1] = __builtin_amdgcn_mfma_f32_16x16x32_bf16(a, b1, acc[mt][1], 0, 0, 0);
    }
    __syncthreads();
  }
#pragma unroll
  for (int mt = 0; mt < 4; mt++)
#pragma unroll
    for (int nt = 0; nt < 2; nt++) {
      int C = bn * 64 + nq * 32 + nt * 16 + lr;
      float bv = bias[C];
      int g = C >> 9, h = C & 511;
      int wgc = h >> 3, jj = h & 7;
#pragma unroll
      for (int r = 0; r < 4; r++) {
        int R = bm * 128 + mq * 64 + mt * 16 + (lane >> 4) * 4 + r;
        int bb = R >> 9, tt = R & 511;
        float v = acc[mt][nt][r] + bv;
        Xperm[(((long long)(tt * 64 + wgc)) * 32 + bb) * 40 + g * 8 + jj] = f2bf(v);
      }
    }
}

// Phase 2: 4 independent sync domains (8 batch rows each) x 64 WGs.
// WG (d, wl) owns hidden cols [8*wl, 8*wl+8) of all 5 gates for batch rows [8d, 8d+8).
// h-broadcast: tagged u64 chunks: (tag = t+1)<<32 | (bf16 h_r | h_i<<16).
// chunk idx c for (row r, col j): c = ((j>>2)*8 + r)*4 + (j&3)  (fragment-major).
// No flags, no fences, no drains: the staging poll IS the sync.
// Poll assignment STRIDED (hb + tid + p*384): each wave-wide load touches 64
// consecutive u64 -> 8 cache lines, fully coalesced (r10 taught us the hard way).
__global__ __launch_bounds__(384) void recur_kernel(
    const unsigned short* __restrict__ WhT,
    const unsigned short* __restrict__ Xperm,
    unsigned long long* __restrict__ Hbuf64,
    float* __restrict__ out) {
  extern __shared__ unsigned short lds[];
  unsigned short* Wl = lds;                            // [40][1032] bf16 (82560 B)
  unsigned int* Hl32 = (unsigned int*)(lds + 41280);   // 8192 u32 (32768 B), frag-major
  float* gates = (float*)((char*)(lds + 41280) + 32768); // [6][16][16] f32 (6144 B)

  int bid = blockIdx.x;
  int d = bid >> 6, wl = bid & 63;
  int tid = threadIdx.x;
  int wave = tid >> 6, lane = tid & 63;
  int nt = wave % 3, kh = wave / 3;      // N-tile, K-half
  int lr = lane & 15, kq = lane >> 4;

  // one-time: stage this WG's 40-column Wh slice into LDS
  for (int idx = tid; idx < 5120; idx += 384) {
    int r = idx >> 7, ch = idx & 127;
    int gcol = (r >> 3) * 512 + wl * 8 + (r & 7);
    uint4 v = *(const uint4*)(WhT + (long long)gcol * 1024 + ch * 8);
    *(uint4*)(&Wl[r * 1032 + ch * 8]) = v;
  }
  // zero Hl (rows 8-15 of each fragment group stay zero forever -> M=8 padding)
  {
    uint4 z = {0u, 0u, 0u, 0u};
    for (int idx = tid; idx < 2048; idx += 384) ((uint4*)Hl32)[idx] = z;
  }

  unsigned long long* Hme = Hbuf64 + d * 8192;
  const int nch = (tid < 256) ? 11 : 10;          // 4096 chunks / 384 threads
  const unsigned need = (tid < 256) ? 0x7FFu : 0x3FFu;

  float c_r = 0.f, c_i = 0.f;
  int er = tid >> 3, ej = tid & 7; // elementwise (row, col) when tid < 64

  for (int t = 0; t < 512; t++) {
    float xg[5];
    if (tid < 64) { // prefetch X pre-activations (latency hides under poll)
      const unsigned short* xp = Xperm + (((long long)(t * 64 + wl)) * 32 + (8 * d + er)) * 40;
#pragma unroll
      for (int g = 0; g < 5; g++) xg[g] = bf2f(xp[g * 8 + ej]);
    }

    if (t > 0) {
      const unsigned long long* hb = Hme + ((t - 1) & 1) * 4096;
      unsigned long long v[11];
      unsigned got = 0;
      while (true) {
#pragma unroll
        for (int p = 0; p < 11; p++)
          if (p < nch && !(got & (1u << p)))
            v[p] = __hip_atomic_load(hb + tid + p * 384, __ATOMIC_RELAXED,
                                     __HIP_MEMORY_SCOPE_AGENT);
        unsigned g2 = got;
#pragma unroll
        for (int p = 0; p < 11; p++)
          if (p < nch && !(got & (1u << p)) && (unsigned)(v[p] >> 32) == (unsigned)t)
            g2 |= 1u << p;
        got = g2;
        if (got == need) break;
        __builtin_amdgcn_s_sleep(1);
      }
#pragma unroll
      for (int p = 0; p < 11; p++)
        if (p < nch) {
          int c = tid + p * 384;
          Hl32[((c >> 5) * 16 + ((c >> 2) & 7)) * 4 + (c & 3)] = (unsigned)v[p];
        }
    }
    __syncthreads(); // B1: staging visible (also covers gates WAR, init zeros at t=0)

    // GEMM: A (16x1024, rows 8-15 zero) @ Wh-slice -> 16x48 (40 used), per wave:
    // N-tile nt, K-half kh (512 K each), two 8-deep dependent chains.
    f32x4 acc0 = {0.f, 0.f, 0.f, 0.f};
    f32x4 acc1 = {0.f, 0.f, 0.f, 0.f};
    const unsigned short* Hls = (const unsigned short*)Hl32;
#pragma unroll
    for (int kk = 0; kk < 8; kk++) {
      int ka = kh * 16 + kk;
      short8 a = *(const short8*)(Hls + (ka * 4 + kq) * 128 + lr * 8);
      short8 b = *(const short8*)(&Wl[(nt * 16 + lr) * 1032 + ka * 32 + kq * 8]);
      acc0 = __builtin_amdgcn_mfma_f32_16x16x32_bf16(a, b, acc0, 0, 0, 0);
    }
#pragma unroll
    for (int kk = 8; kk < 16; kk++) {
      int ka = kh * 16 + kk;
      short8 a = *(const short8*)(Hls + (ka * 4 + kq) * 128 + lr * 8);
      short8 b = *(const short8*)(&Wl[(nt * 16 + lr) * 1032 + ka * 32 + kq * 8]);
      acc1 = __builtin_amdgcn_mfma_f32_16x16x32_bf16(a, b, acc1, 0, 0, 0);
    }
    {
      int r0 = (lane >> 4) * 4;
#pragma unroll
      for (int r = 0; r < 4; r++)
        gates[wave * 256 + (r0 + r) * 16 + lr] = acc0[r] + acc1[r];
    }
    __syncthreads(); // B2: gates write -> read

    if (tid < 64) {
      float gv[5];
#pragma unroll
      for (int g = 0; g < 5; g++) {
        int c = g * 8 + ej, tn = c >> 4, cw = c & 15;
        gv[g] = gates[tn * 256 + er * 16 + cw] + gates[(3 + tn) * 256 + er * 16 + cw] + xg[g];
      }
      float ig = 1.f / (1.f + __expf(-gv[0]));
      float fg = 1.f / (1.f + __expf(-gv[1]));
      float og = 1.f / (1.f + __expf(-gv[2]));
      float crp = gv[3], cip = gv[4];
      float mag = fmaxf(sqrtf(crp * crp + cip * cip + 1e-14f), 1e-8f);
      float e1 = __expf(-2.f * mag);
      float s1 = (1.f - e1) * __frcp_rn((1.f + e1) * mag);
      c_r = fg * c_r + ig * (crp * s1);
      c_i = fg * c_i + ig * (cip * s1);
      float mag2 = fmaxf(sqrtf(c_r * c_r + c_i * c_i + 1e-14f), 1e-8f);
      float e2 = __expf(-2.f * mag2);
      float s2 = (1.f - e2) * __frcp_rn((1.f + e2) * mag2);
      float hr = og * (c_r * s2);
      float hi = og * (c_i * s2);
      // tagged broadcast chunk: single atomic u64, no drain/flag/fence needed
      int j = wl * 8 + ej;
      int cidx = ((j >> 2) * 8 + er) * 4 + (j & 3);
      unsigned hv = (unsigned)f2bf(hr) | ((unsigned)f2bf(hi) << 16);
      __hip_atomic_store(Hme + (t & 1) * 4096 + cidx,
                         ((unsigned long long)(t + 1) << 32) | hv,
                         __ATOMIC_RELAXED, __HIP_MEMORY_SCOPE_AGENT);
      // shadow HBM output stores (overlap next step's poll)
      int b = 8 * d + er;
      out[(long long)b * 262144 + t * 512 + j] = hr;
      out[8388608ll + (long long)b * 262144 + t * 512 + j] = hi;
      if (t == 511) {
        out[16777216ll + b * 512 + j] = hr;
        out[16793600ll + b * 512 + j] = hi;
        out[16809984ll + b * 512 + j] = c_r;
        out[16826368ll + b * 512 + j] = c_i;
      }
    }
    // waves 1-5 proceed directly to next step's poll (overlaps wave0 elementwise)
  }
}

extern "C" void kernel_launch(void* const* d_in, const int* in_sizes, int n_in,
                              void* d_out, int out_size, void* d_ws, size_t ws_size,
                              hipStream_t stream) {
  const float* zr = (const float*)d_in[0];
  const float* zi = (const float*)d_in[1];
  // input group bases: i=2, f=8, c=14, o=20; within: WzR,WzI,WhR,WhI,bR,bI
  const int gi = 2, gf = 8, gc = 14, go = 20;
  PackArgs pa;
  const int gbase[5] = {gi, gf, go, gc, gc}; // internal g: 0=i,1=f,2=o,3=cr,4=ci
  for (int g = 0; g < 5; g++) {
    int b = gbase[g];
    if (g < 4) {
      pa.zlo[g] = (const float*)d_in[b + 0];
      pa.zhi[g] = (const float*)d_in[b + 1];
      pa.hlo[g] = (const float*)d_in[b + 2];
      pa.hhi[g] = (const float*)d_in[b + 3];
    } else { // ci: "lo" (real-mult) uses imag weight (+), "hi" (imag-mult) uses real weight (+)
      pa.zlo[g] = (const float*)d_in[b + 1];
      pa.zhi[g] = (const float*)d_in[b + 0];
      pa.hlo[g] = (const float*)d_in[b + 3];
      pa.hhi[g] = (const float*)d_in[b + 2];
    }
  }
  pa.bias[0] = (const float*)d_in[gi + 4];
  pa.bias[1] = (const float*)d_in[gf + 4];
  pa.bias[2] = (const float*)d_in[go + 4];
  pa.bias[3] = (const float*)d_in[gc + 4];
  pa.bias[4] = (const float*)d_in[gc + 5];

  char* ws = (char*)d_ws;
  unsigned short* WzT = (unsigned short*)(ws + OFF_WZT);
  unsigned short* WhT = (unsigned short*)(ws + OFF_WHT);
  float* bias = (float*)(ws + OFF_BIAS);
  unsigned short* Xperm = (unsigned short*)(ws + OFF_XPERM);
  unsigned long long* Hbuf64 = (unsigned long long*)(ws + OFF_HBUF);

  pack_kernel<<<2048, 256, 0, stream>>>(pa, WzT, WhT, bias, Hbuf64);
  phase1_kernel<<<5120, 256, 0, stream>>>(zr, zi, WzT, bias, Xperm);

  const int ldsBytes = 82560 + 32768 + 6144; // 121472
  (void)hipFuncSetAttribute((const void*)recur_kernel,
                            hipFuncAttributeMaxDynamicSharedMemorySize, ldsBytes);
  recur_kernel<<<NWG, 384, ldsBytes, stream>>>(WhT, Xperm, Hbuf64, (float*)d_out);
}

// Round 13
// 1739.147 us; speedup vs baseline: 3.1066x; 1.0230x over previous
//
#include <hip/hip_runtime.h>

// ComplexLSTM: B=32,S=512,I=512,H=512
// ws layout (bytes)
#define OFF_WZT   0ull
#define OFF_WHT   5242880ull
#define OFF_BIAS  10485760ull
#define OFF_XPERM 10496000ull
#define OFF_HBUF  94382080ull   // 4 domains x 2 bufs x 4096 u64 = 262144 B
#define NWG 256

typedef __attribute__((ext_vector_type(8))) short short8;
typedef __attribute__((ext_vector_type(4))) float f32x4;

__device__ __forceinline__ unsigned short f2bf(float f) {
  unsigned int u = __float_as_uint(f);
  u += 0x7fffu + ((u >> 16) & 1u);
  return (unsigned short)(u >> 16);
}
__device__ __forceinline__ float bf2f(unsigned short h) {
  return __uint_as_float(((unsigned int)h) << 16);
}

struct PackArgs {
  const float* zlo[5]; const float* zhi[5];
  const float* hlo[5]; const float* hhi[5];
  const float* bias[5];
};

// Transposing pack (LDS-tiled, coalesced both sides).
// WzT[c][k]: k<512 -> z_r coeff (col k), k>=512 -> z_i coeff.
// WhT[c][k]: K interleaved: k=2*kk+ri, ri=0 -> h_r[kk], ri=1 -> h_i[kk].
// c = g*512+h (g: 0=i,1=f,2=o,3=cr,4=ci)
// Jobs 0..639: WzT — g=j>>7, half=(j>>6)&1, tile=j&63 (th=tile&7, tk=tile>>3).
// Jobs 640..959: WhT fused lo/hi — g=(j-640)>>6, tile=(j-640)&63.
__global__ __launch_bounds__(256) void pack_kernel(
    PackArgs args, unsigned short* __restrict__ WzT,
    unsigned short* __restrict__ WhT,
    float* __restrict__ bias_out,
    unsigned long long* __restrict__ Hbuf64) {
  __shared__ float T0[64][65];
  __shared__ float T1[64][65];
  int j = blockIdx.x;
  int tid = threadIdx.x;
  int rr = tid >> 6, cc = tid & 63;

  if (j < 640) {
    int g = j >> 7, half = (j >> 6) & 1, tile = j & 63;
    int th = tile & 7, tk = tile >> 3;
    const float* src = half ? args.zhi[g] : args.zlo[g];
    float sgn = (half == 0 || g == 4) ? 1.f : -1.f;
#pragma unroll
    for (int p = 0; p < 16; p++) {
      int r = p * 4 + rr;  // kk_local
      T0[r][cc] = sgn * src[(tk * 64 + r) * 512 + th * 64 + cc];
    }
    __syncthreads();
    int cl = tid >> 2, q = tid & 3;
    int c = g * 512 + th * 64 + cl;
    unsigned int w[8];
#pragma unroll
    for (int i = 0; i < 8; i++) {
      int kk = q * 16 + i * 2;
      w[i] = (unsigned)f2bf(T0[kk][cl]) | ((unsigned)f2bf(T0[kk + 1][cl]) << 16);
    }
    unsigned short* dst = WzT + (long long)c * 1024 + half * 512 + tk * 64 + q * 16;
    *(uint4*)dst = *(uint4*)&w[0];
    *(uint4*)(dst + 8) = *(uint4*)&w[4];
  } else {
    int j2 = j - 640;
    int g = j2 >> 6, tile = j2 & 63;
    int th = tile & 7, tk = tile >> 3;
    const float* slo = args.hlo[g];
    const float* shi = args.hhi[g];
    float sghi = (g == 4) ? 1.f : -1.f;
#pragma unroll
    for (int p = 0; p < 16; p++) {
      int r = p * 4 + rr;
      T0[r][cc] = slo[(tk * 64 + r) * 512 + th * 64 + cc];
      T1[r][cc] = sghi * shi[(tk * 64 + r) * 512 + th * 64 + cc];
    }
    __syncthreads();
    int cl = tid >> 2, q = tid & 3;
    int c = g * 512 + th * 64 + cl;
    unsigned int w[16];
#pragma unroll
    for (int i = 0; i < 16; i++) {
      int kk = q * 16 + i;
      w[i] = (unsigned)f2bf(T0[kk][cl]) | ((unsigned)f2bf(T1[kk][cl]) << 16);
    }
    unsigned short* dst = WhT + (long long)c * 1024 + tk * 128 + q * 32;
#pragma unroll
    for (int i = 0; i < 4; i++)
      *(uint4*)(dst + i * 8) = *(uint4*)&w[i * 4];
  }

  int gid0 = blockIdx.x * 256 + threadIdx.x;
  if (gid0 < 2560) { int g = gid0 >> 9; bias_out[gid0] = args.bias[g][gid0 & 511]; }
  if (gid0 < 32768) Hbuf64[gid0] = 0ull; // clear all tags (replay safety)
}

// Phase 1: X = [z_r|z_i](16384x1024) @ WzT^T + bias -> bf16, permuted to [t][wg][b][40]
// 128x64 tile per 256-thread block (4 waves, each 64 rows x 32 cols; 8 MFMA/K-step).
__global__ __launch_bounds__(256) void phase1_kernel(
    const float* __restrict__ zr, const float* __restrict__ zi,
    const unsigned short* __restrict__ WzT, const float* __restrict__ bias,
    unsigned short* __restrict__ Xperm) {
  __shared__ unsigned short Al[128 * 40];
  __shared__ unsigned short Bl[64 * 40];
  int bid = blockIdx.x;
  int bm = bid / 40, bn = bid % 40;
  int tid = threadIdx.x;
  int wave = tid >> 6, lane = tid & 63;
  int mq = wave >> 1, nq = wave & 1;
  int lr = lane & 15, lkb = (lane >> 4) * 8;
  int arow = tid >> 1, aq = tid & 1;   // A staging: 2 thr/row, 16 elems each
  int brow = tid >> 2, bq = tid & 3;   // B staging: 4 thr/row, 8 elems each

  f32x4 acc[4][2];
#pragma unroll
  for (int i0 = 0; i0 < 4; i0++)
#pragma unroll
    for (int j0 = 0; j0 < 2; j0++) acc[i0][j0] = (f32x4){0.f, 0.f, 0.f, 0.f};

  for (int kb = 0; kb < 32; kb++) {
    {
      int gk = kb * 32 + aq * 16;
      const float* srcp = (gk < 512)
          ? (zr + (long long)(bm * 128 + arow) * 512 + gk)
          : (zi + (long long)(bm * 128 + arow) * 512 + (gk - 512));
      float4 f0 = *(const float4*)srcp;
      float4 f1 = *(const float4*)(srcp + 4);
      float4 f2 = *(const float4*)(srcp + 8);
      float4 f3 = *(const float4*)(srcp + 12);
      uint4 p0, p1;
      p0.x = (unsigned)f2bf(f0.x) | ((unsigned)f2bf(f0.y) << 16);
      p0.y = (unsigned)f2bf(f0.z) | ((unsigned)f2bf(f0.w) << 16);
      p0.z = (unsigned)f2bf(f1.x) | ((unsigned)f2bf(f1.y) << 16);
      p0.w = (unsigned)f2bf(f1.z) | ((unsigned)f2bf(f1.w) << 16);
      p1.x = (unsigned)f2bf(f2.x) | ((unsigned)f2bf(f2.y) << 16);
      p1.y = (unsigned)f2bf(f2.z) | ((unsigned)f2bf(f2.w) << 16);
      p1.z = (unsigned)f2bf(f3.x) | ((unsigned)f2bf(f3.y) << 16);
      p1.w = (unsigned)f2bf(f3.z) | ((unsigned)f2bf(f3.w) << 16);
      *(uint4*)(&Al[arow * 40 + aq * 16]) = p0;
      *(uint4*)(&Al[arow * 40 + aq * 16 + 8]) = p1;
    }
    {
      const unsigned short* bsrc = WzT + (long long)(bn * 64 + brow) * 1024 + kb * 32 + bq * 8;
      *(uint4*)(&Bl[brow * 40 + bq * 8]) = *(const uint4*)bsrc;
    }
    __syncthreads();
    short8 b0 = *(const short8*)(&Bl[(nq * 32 + 0 + lr) * 40 + lkb]);
    short8 b1 = *(const short8*)(&Bl[(nq * 32 + 16 + lr) * 40 + lkb]);
#pragma unroll
    for (int mt = 0; mt < 4; mt++) {
      short8 a = *(const short8*)(&Al[(mq * 64 + mt * 16 + lr) * 40 + lkb]);
      acc[mt][0] = __builtin_amdgcn_mfma_f32_16x16x32_bf16(a, b0, acc[mt][0], 0, 0, 0);
      acc[mt][1] = __builtin_amdgcn_mfma_f32_16x16x32_bf16(a, b1, acc[mt][1], 0, 0, 0);
    }
    __syncthreads();
  }
#pragma unroll
  for (int mt = 0; mt < 4; mt++)
#pragma unroll
    for (int nt = 0; nt < 2; nt++) {
      int C = bn * 64 + nq * 32 + nt * 16 + lr;
      float bv = bias[C];
      int g = C >> 9, h = C & 511;
      int wgc = h >> 3, jj = h & 7;
#pragma unroll
      for (int r = 0; r < 4; r++) {
        int R = bm * 128 + mq * 64 + mt * 16 + (lane >> 4) * 4 + r;
        int bb = R >> 9, tt = R & 511;
        float v = acc[mt][nt][r] + bv;
        Xperm[(((long long)(tt * 64 + wgc)) * 32 + bb) * 40 + g * 8 + jj] = f2bf(v);
      }
    }
}

// Phase 2: 4 independent sync domains (8 batch rows each) x 64 WGs.
// WG (d, wl) owns hidden cols [8*wl, 8*wl+8) of all 5 gates for batch rows [8d, 8d+8).
// h-broadcast: tagged u64 chunks: (tag = t+1)<<32 | (bf16 h_r | h_i<<16).
// chunk idx c for (row r, col j): c = ((j>>2)*8 + r)*4 + (j&3)  (fragment-major).
// No flags, no fences, no drains: the staging poll IS the sync.
// Poll assignment STRIDED (hb + tid + p*384): each wave-wide load touches 64
// consecutive u64 -> 8 cache lines, fully coalesced (r10 taught us the hard way).
__global__ __launch_bounds__(384) void recur_kernel(
    const unsigned short* __restrict__ WhT,
    const unsigned short* __restrict__ Xperm,
    unsigned long long* __restrict__ Hbuf64,
    float* __restrict__ out) {
  extern __shared__ unsigned short lds[];
  unsigned short* Wl = lds;                            // [40][1032] bf16 (82560 B)
  unsigned int* Hl32 = (unsigned int*)(lds + 41280);   // 8192 u32 (32768 B), frag-major
  float* gates = (float*)((char*)(lds + 41280) + 32768); // [6][16][16] f32 (6144 B)

  int bid = blockIdx.x;
  int d = bid >> 6, wl = bid & 63;
  int tid = threadIdx.x;
  int wave = tid >> 6, lane = tid & 63;
  int nt = wave % 3, kh = wave / 3;      // N-tile, K-half
  int lr = lane & 15, kq = lane >> 4;

  // one-time: stage this WG's 40-column Wh slice into LDS
  for (int idx = tid; idx < 5120; idx += 384) {
    int r = idx >> 7, ch = idx & 127;
    int gcol = (r >> 3) * 512 + wl * 8 + (r & 7);
    uint4 v = *(const uint4*)(WhT + (long long)gcol * 1024 + ch * 8);
    *(uint4*)(&Wl[r * 1032 + ch * 8]) = v;
  }
  // zero Hl (rows 8-15 of each fragment group stay zero forever -> M=8 padding)
  {
    uint4 z = {0u, 0u, 0u, 0u};
    for (int idx = tid; idx < 2048; idx += 384) ((uint4*)Hl32)[idx] = z;
  }

  unsigned long long* Hme = Hbuf64 + d * 8192;
  const int nch = (tid < 256) ? 11 : 10;          // 4096 chunks / 384 threads
  const unsigned need = (tid < 256) ? 0x7FFu : 0x3FFu;

  float c_r = 0.f, c_i = 0.f;
  int er = tid >> 3, ej = tid & 7; // elementwise (row, col) when tid < 64

  for (int t = 0; t < 512; t++) {
    float xg[5];
    if (tid < 64) { // prefetch X pre-activations (latency hides under poll)
      const unsigned short* xp = Xperm + (((long long)(t * 64 + wl)) * 32 + (8 * d + er)) * 40;
#pragma unroll
      for (int g = 0; g < 5; g++) xg[g] = bf2f(xp[g * 8 + ej]);
    }

    if (t > 0) {
      const unsigned long long* hb = Hme + ((t - 1) & 1) * 4096;
      unsigned long long v[11];
      unsigned got = 0;
      while (true) {
#pragma unroll
        for (int p = 0; p < 11; p++)
          if (p < nch && !(got & (1u << p)))
            v[p] = __hip_atomic_load(hb + tid + p * 384, __ATOMIC_RELAXED,
                                     __HIP_MEMORY_SCOPE_AGENT);
        unsigned g2 = got;
#pragma unroll
        for (int p = 0; p < 11; p++)
          if (p < nch && !(got & (1u << p)) && (unsigned)(v[p] >> 32) == (unsigned)t)
            g2 |= 1u << p;
        got = g2;
        if (got == need) break;
        __builtin_amdgcn_s_sleep(1);
      }
#pragma unroll
      for (int p = 0; p < 11; p++)
        if (p < nch) {
          int c = tid + p * 384;
          Hl32[((c >> 5) * 16 + ((c >> 2) & 7)) * 4 + (c & 3)] = (unsigned)v[p];
        }
    }
    __syncthreads(); // B1: staging visible (also covers gates WAR, init zeros at t=0)

    // GEMM: A (16x1024, rows 8-15 zero) @ Wh-slice -> 16x48 (40 used), per wave:
    // N-tile nt, K-half kh (512 K each), two 8-deep dependent chains.
    f32x4 acc0 = {0.f, 0.f, 0.f, 0.f};
    f32x4 acc1 = {0.f, 0.f, 0.f, 0.f};
    const unsigned short* Hls = (const unsigned short*)Hl32;
#pragma unroll
    for (int kk = 0; kk < 8; kk++) {
      int ka = kh * 16 + kk;
      short8 a = *(const short8*)(Hls + (ka * 4 + kq) * 128 + lr * 8);
      short8 b = *(const short8*)(&Wl[(nt * 16 + lr) * 1032 + ka * 32 + kq * 8]);
      acc0 = __builtin_amdgcn_mfma_f32_16x16x32_bf16(a, b, acc0, 0, 0, 0);
    }
#pragma unroll
    for (int kk = 8; kk < 16; kk++) {
      int ka = kh * 16 + kk;
      short8 a = *(const short8*)(Hls + (ka * 4 + kq) * 128 + lr * 8);
      short8 b = *(const short8*)(&Wl[(nt * 16 + lr) * 1032 + ka * 32 + kq * 8]);
      acc1 = __builtin_amdgcn_mfma_f32_16x16x32_bf16(a, b, acc1, 0, 0, 0);
    }
    {
      int r0 = (lane >> 4) * 4;
#pragma unroll
      for (int r = 0; r < 4; r++)
        gates[wave * 256 + (r0 + r) * 16 + lr] = acc0[r] + acc1[r];
    }
    __syncthreads(); // B2: gates write -> read

    if (tid < 64) {
      float gv[5];
#pragma unroll
      for (int g = 0; g < 5; g++) {
        int c = g * 8 + ej, tn = c >> 4, cw = c & 15;
        gv[g] = gates[tn * 256 + er * 16 + cw] + gates[(3 + tn) * 256 + er * 16 + cw] + xg[g];
      }
      float ig = 1.f / (1.f + __expf(-gv[0]));
      float fg = 1.f / (1.f + __expf(-gv[1]));
      float og = 1.f / (1.f + __expf(-gv[2]));
      float crp = gv[3], cip = gv[4];
      float mag = fmaxf(sqrtf(crp * crp + cip * cip + 1e-14f), 1e-8f);
      float e1 = __expf(-2.f * mag);
      float s1 = (1.f - e1) * __frcp_rn((1.f + e1) * mag);
      c_r = fg * c_r + ig * (crp * s1);
      c_i = fg * c_i + ig * (cip * s1);
      float mag2 = fmaxf(sqrtf(c_r * c_r + c_i * c_i + 1e-14f), 1e-8f);
      float e2 = __expf(-2.f * mag2);
      float s2 = (1.f - e2) * __frcp_rn((1.f + e2) * mag2);
      float hr = og * (c_r * s2);
      float hi = og * (c_i * s2);
      // tagged broadcast chunk: single atomic u64, no drain/flag/fence needed
      int j = wl * 8 + ej;
      int cidx = ((j >> 2) * 8 + er) * 4 + (j & 3);
      unsigned hv = (unsigned)f2bf(hr) | ((unsigned)f2bf(hi) << 16);
      __hip_atomic_store(Hme + (t & 1) * 4096 + cidx,
                         ((unsigned long long)(t + 1) << 32) | hv,
                         __ATOMIC_RELAXED, __HIP_MEMORY_SCOPE_AGENT);
      // shadow HBM output stores (overlap next step's poll)
      int b = 8 * d + er;
      out[(long long)b * 262144 + t * 512 + j] = hr;
      out[8388608ll + (long long)b * 262144 + t * 512 + j] = hi;
      if (t == 511) {
        out[16777216ll + b * 512 + j] = hr;
        out[16793600ll + b * 512 + j] = hi;
        out[16809984ll + b * 512 + j] = c_r;
        out[16826368ll + b * 512 + j] = c_i;
      }
    }
    // waves 1-5 proceed directly to next step's poll (overlaps wave0 elementwise)
  }
}

extern "C" void kernel_launch(void* const* d_in, const int* in_sizes, int n_in,
                              void* d_out, int out_size, void* d_ws, size_t ws_size,
                              hipStream_t stream) {
  const float* zr = (const float*)d_in[0];
  const float* zi = (const float*)d_in[1];
  // input group bases: i=2, f=8, c=14, o=20; within: WzR,WzI,WhR,WhI,bR,bI
  const int gi = 2, gf = 8, gc = 14, go = 20;
  PackArgs pa;
  const int gbase[5] = {gi, gf, go, gc, gc}; // internal g: 0=i,1=f,2=o,3=cr,4=ci
  for (int g = 0; g < 5; g++) {
    int b = gbase[g];
    if (g < 4) {
      pa.zlo[g] = (const float*)d_in[b + 0];
      pa.zhi[g] = (const float*)d_in[b + 1];
      pa.hlo[g] = (const float*)d_in[b + 2];
      pa.hhi[g] = (const float*)d_in[b + 3];
    } else { // ci: "lo" (real-mult) uses imag weight (+), "hi" (imag-mult) uses real weight (+)
      pa.zlo[g] = (const float*)d_in[b + 1];
      pa.zhi[g] = (const float*)d_in[b + 0];
      pa.hlo[g] = (const float*)d_in[b + 3];
      pa.hhi[g] = (const float*)d_in[b + 2];
    }
  }
  pa.bias[0] = (const float*)d_in[gi + 4];
  pa.bias[1] = (const float*)d_in[gf + 4];
  pa.bias[2] = (const float*)d_in[go + 4];
  pa.bias[3] = (const float*)d_in[gc + 4];
  pa.bias[4] = (const float*)d_in[gc + 5];

  char* ws = (char*)d_ws;
  unsigned short* WzT = (unsigned short*)(ws + OFF_WZT);
  unsigned short* WhT = (unsigned short*)(ws + OFF_WHT);
  float* bias = (float*)(ws + OFF_BIAS);
  unsigned short* Xperm = (unsigned short*)(ws + OFF_XPERM);
  unsigned long long* Hbuf64 = (unsigned long long*)(ws + OFF_HBUF);

  pack_kernel<<<960, 256, 0, stream>>>(pa, WzT, WhT, bias, Hbuf64);
  phase1_kernel<<<5120, 256, 0, stream>>>(zr, zi, WzT, bias, Xperm);

  const int ldsBytes = 82560 + 32768 + 6144; // 121472
  (void)hipFuncSetAttribute((const void*)recur_kernel,
                            hipFuncAttributeMaxDynamicSharedMemorySize, ldsBytes);
  recur_kernel<<<NWG, 384, ldsBytes, stream>>>(WhT, Xperm, Hbuf64, (float*)d_out);
}